// Round 8
// baseline (38.581 us; speedup 1.0000x reference)
//
#include <hip/hip_runtime.h>
#include <float.h>

#define NS 50
#define NP 64              // padded to power of two for bitonic network
#define B_DIM 8192
#define D_DIM 64
#define BD (B_DIM * D_DIM)
#define BLOCK 256
#define GRID (BD / BLOCK)  // 2048

typedef const __attribute__((address_space(1))) float gfloat;
typedef __attribute__((address_space(3))) float lfloat;

__device__ __forceinline__ float block_reduce(float e, int tid) {
    #pragma unroll
    for (int off = 32; off > 0; off >>= 1)
        e += __shfl_down(e, off, 64);
    __shared__ float wsum[BLOCK / 64];
    const int lane = tid & 63;
    const int wid  = tid >> 6;
    if (lane == 0) wsum[wid] = e;
    __syncthreads();
    float bs = 0.0f;
    if (tid == 0) {
        #pragma unroll
        for (int w = 0; w < BLOCK / 64; ++w) bs += wsum[w];
    }
    return bs;
}

// Compute the per-element energy from LDS column + params (verified R2-R7).
__device__ __forceinline__ float elem_energy_lds(const float* tile, int tid,
                                                 float m, float sd, float t) {
    float s[NP];
    float f0 = 0.0f, f1 = 0.0f;
    #pragma unroll
    for (int k = 0; k < NS; ++k) {
        float nz = tile[k * BLOCK + tid];
        s[k] = fmaf(nz, sd, m);
        float d = fabsf(s[k] - t);
        if (k & 1) f1 += d;
        else       f0 += d;
    }
    #pragma unroll
    for (int k = NS; k < NP; ++k) s[k] = FLT_MAX;

    // Bitonic sort network, 64 elems, fully unrolled, compile-time dirs.
    #pragma unroll
    for (int k = 2; k <= NP; k <<= 1) {
        #pragma unroll
        for (int j = k >> 1; j > 0; j >>= 1) {
            #pragma unroll
            for (int i = 0; i < NP; ++i) {
                const int l = i ^ j;
                if (l > i) {
                    const bool up = ((i & k) == 0);
                    float a = s[i], b = s[l];
                    float lo = fminf(a, b);
                    float hi = fmaxf(a, b);
                    s[i] = up ? lo : hi;
                    s[l] = up ? hi : lo;
                }
            }
        }
    }

    // sum_{i<j}|s_i-s_j| == sum_k (2k-(n-1)) * sorted_k
    float p0 = 0.0f, p1 = 0.0f;
    #pragma unroll
    for (int k = 0; k < NS; ++k) {
        const float c = (float)(2 * k - (NS - 1));
        if (k & 1) p1 = fmaf(c, s[k], p1);
        else       p0 = fmaf(c, s[k], p0);
    }
    float e = (f0 + f1) * (1.0f / NS) - (p0 + p1) * (1.0f / 2450.0f);
    return e * (1.0f / (float)BD);   // pre-scale for global mean
}

// Stage 1: async-stage the block's 50x256 noise tile into LDS
// (fire-and-forget, no VGPR destinations, one vmcnt drain at the barrier),
// then per-thread bitonic pipeline. XCD-swizzled block order; plain store.
__global__ __launch_bounds__(BLOCK, 3) void energy_partial_kernel(
    const float* __restrict__ mean, const float* __restrict__ variance,
    const float* __restrict__ noise, const float* __restrict__ target,
    float* __restrict__ partial) {

    __shared__ float tile[NS * BLOCK];   // 50 KB

    const int tid  = threadIdx.x;
    const int lane = tid & 63;
    const int wid  = tid >> 6;
    // Bijective XCD swizzle (GRID % 8 == 0): contiguous windows per XCD.
    const int wg   = (blockIdx.x & 7) * (GRID / 8) + (blockIdx.x >> 3);
    const size_t blockOff = (size_t)wg * BLOCK;

    // ---- Async stage: wave w stages rows k = w, w+4, ... Each instruction
    // moves 64 lanes x 16B = one full 1KB row. ~13 in flight per wave.
    #pragma unroll
    for (int k = wid; k < NS; k += 4) {
        gfloat* g = (gfloat*)(noise + (size_t)k * BD + blockOff + (size_t)lane * 4);
        lfloat* l = (lfloat*)(tile + k * BLOCK);  // wave-uniform base; HW adds lane*16B
        __builtin_amdgcn_global_load_lds(g, l, 16, 0, 0);
    }

    const int idx = (int)blockOff + tid;
    const float m = mean[idx];
    const float v = variance[idx];
    const float t = target[idx];
    const float sd = sqrtf(v + 1e-6f);

    __syncthreads();   // vmcnt(0) drain + barrier

    float e = elem_energy_lds(tile, tid, m, sd, t);
    float bs = block_reduce(e, tid);
    if (tid == 0) partial[blockIdx.x] = bs;
}

// Stage 2: one block sums the 2048 partials, writes the scalar output.
__global__ __launch_bounds__(BLOCK) void reduce_partial_kernel(
    const float* __restrict__ partial, float* __restrict__ out) {
    float e = 0.0f;
    #pragma unroll
    for (int i = 0; i < GRID / BLOCK; ++i)
        e += partial[i * BLOCK + threadIdx.x];
    float bs = block_reduce(e, threadIdx.x);
    if (threadIdx.x == 0) out[0] = bs;   // overwrites poison
}

// Fallback (ws too small): single-kernel atomic path, same structure.
__global__ __launch_bounds__(BLOCK, 3) void energy_atomic_kernel(
    const float* __restrict__ mean, const float* __restrict__ variance,
    const float* __restrict__ noise, const float* __restrict__ target,
    float* __restrict__ out) {
    __shared__ float tile[NS * BLOCK];
    const int tid  = threadIdx.x;
    const int lane = tid & 63;
    const int wid  = tid >> 6;
    const int wg   = (blockIdx.x & 7) * (GRID / 8) + (blockIdx.x >> 3);
    const size_t blockOff = (size_t)wg * BLOCK;
    #pragma unroll
    for (int k = wid; k < NS; k += 4) {
        gfloat* g = (gfloat*)(noise + (size_t)k * BD + blockOff + (size_t)lane * 4);
        lfloat* l = (lfloat*)(tile + k * BLOCK);
        __builtin_amdgcn_global_load_lds(g, l, 16, 0, 0);
    }
    const int idx = (int)blockOff + tid;
    const float m = mean[idx];
    const float v = variance[idx];
    const float t = target[idx];
    const float sd = sqrtf(v + 1e-6f);
    __syncthreads();
    float e = elem_energy_lds(tile, tid, m, sd, t);
    float bs = block_reduce(e, tid);
    if (tid == 0) atomicAdd(out, bs);
}

extern "C" void kernel_launch(void* const* d_in, const int* in_sizes, int n_in,
                              void* d_out, int out_size, void* d_ws, size_t ws_size,
                              hipStream_t stream) {
    const float* mean     = (const float*)d_in[0];
    const float* variance = (const float*)d_in[1];
    const float* noise    = (const float*)d_in[2];
    const float* target   = (const float*)d_in[3];
    float* out = (float*)d_out;

    if (ws_size >= (size_t)GRID * sizeof(float)) {
        float* partial = (float*)d_ws;
        energy_partial_kernel<<<GRID, BLOCK, 0, stream>>>(mean, variance, noise,
                                                          target, partial);
        reduce_partial_kernel<<<1, BLOCK, 0, stream>>>(partial, out);
    } else {
        hipMemsetAsync(out, 0, sizeof(float), stream);
        energy_atomic_kernel<<<GRID, BLOCK, 0, stream>>>(mean, variance, noise,
                                                         target, out);
    }
}

// Round 9
// 33.798 us; speedup vs baseline: 1.1415x; 1.1415x over previous
//
#include <hip/hip_runtime.h>
#include <float.h>

#define NS 50
#define NP 64              // padded to power of two for bitonic network
#define B_DIM 8192
#define D_DIM 64
#define BD (B_DIM * D_DIM)
#define BLOCK 256
#define GRID (BD / BLOCK)  // 2048

__device__ __forceinline__ float block_reduce(float e, int tid) {
    #pragma unroll
    for (int off = 32; off > 0; off >>= 1)
        e += __shfl_down(e, off, 64);
    __shared__ float wsum[BLOCK / 64];
    const int lane = tid & 63;
    const int wid  = tid >> 6;
    if (lane == 0) wsum[wid] = e;
    __syncthreads();
    float bs = 0.0f;
    if (tid == 0) {
        #pragma unroll
        for (int w = 0; w < BLOCK / 64; ++w) bs += wsum[w];
    }
    return bs;
}

// Per-element energy with FORCED memory-level parallelism: 50 inline-asm
// global_load_dword issued back-to-back (compiler cannot re-batch them),
// one explicit vmcnt(0) drain, sched_barrier fence, then compute.
__device__ __forceinline__ float energy_elem_mlp(const float* __restrict__ mean,
                                                 const float* __restrict__ variance,
                                                 const float* __restrict__ noise,
                                                 const float* __restrict__ target,
                                                 int idx) {
    float s[NP];
    const unsigned voff = (unsigned)idx * 4u;   // byte offset of column idx
    // 50 loads, all outstanding simultaneously (single SGPR base; per-row
    // 2MB stride folded into the 32-bit VGPR offset: max 100MB < 4GB).
    #pragma unroll
    for (int k = 0; k < NS; ++k) {
        const unsigned off_k = voff + (unsigned)k * (unsigned)(BD * 4);
        asm volatile("global_load_dword %0, %1, %2"
                     : "=v"(s[k])
                     : "v"(off_k), "s"(noise));
    }

    const float m = mean[idx];
    const float v = variance[idx];
    const float t = target[idx];
    const float sd = sqrtf(v + 1e-6f);

    // Drain ALL outstanding vmem (covers the 50 asm loads + params), then
    // fence the scheduler so no consumer is hoisted above the wait (rule #18).
    asm volatile("s_waitcnt vmcnt(0)" ::: "memory");
    __builtin_amdgcn_sched_barrier(0);

    float f0 = 0.0f, f1 = 0.0f;
    #pragma unroll
    for (int k = 0; k < NS; ++k) {
        s[k] = fmaf(s[k], sd, m);
        float d = fabsf(s[k] - t);
        if (k & 1) f1 += d;
        else       f0 += d;
    }
    #pragma unroll
    for (int k = NS; k < NP; ++k) s[k] = FLT_MAX;

    // Bitonic sort network, 64 elems, fully unrolled, compile-time dirs.
    #pragma unroll
    for (int k = 2; k <= NP; k <<= 1) {
        #pragma unroll
        for (int j = k >> 1; j > 0; j >>= 1) {
            #pragma unroll
            for (int i = 0; i < NP; ++i) {
                const int l = i ^ j;
                if (l > i) {
                    const bool up = ((i & k) == 0);
                    float a = s[i], b = s[l];
                    float lo = fminf(a, b);
                    float hi = fmaxf(a, b);
                    s[i] = up ? lo : hi;
                    s[l] = up ? hi : lo;
                }
            }
        }
    }

    // sum_{i<j}|s_i-s_j| == sum_k (2k-(n-1)) * sorted_k
    float p0 = 0.0f, p1 = 0.0f;
    #pragma unroll
    for (int k = 0; k < NS; ++k) {
        const float c = (float)(2 * k - (NS - 1));
        if (k & 1) p1 = fmaf(c, s[k], p1);
        else       p0 = fmaf(c, s[k], p0);
    }

    float e = (f0 + f1) * (1.0f / NS) - (p0 + p1) * (1.0f / 2450.0f);
    return e * (1.0f / (float)BD);   // pre-scale for global mean
}

// Stage 1: per-block partial sum -> plain store (no atomics), XCD-swizzled.
__global__ __launch_bounds__(BLOCK) void energy_partial_kernel(
    const float* __restrict__ mean, const float* __restrict__ variance,
    const float* __restrict__ noise, const float* __restrict__ target,
    float* __restrict__ partial) {
    const int wg  = (blockIdx.x & 7) * (GRID / 8) + (blockIdx.x >> 3);
    const int idx = wg * BLOCK + threadIdx.x;
    float e = energy_elem_mlp(mean, variance, noise, target, idx);
    float bs = block_reduce(e, threadIdx.x);
    if (threadIdx.x == 0) partial[blockIdx.x] = bs;
}

// Stage 2: one block sums the 2048 partials, writes the scalar output.
__global__ __launch_bounds__(BLOCK) void reduce_partial_kernel(
    const float* __restrict__ partial, float* __restrict__ out) {
    float e = 0.0f;
    #pragma unroll
    for (int i = 0; i < GRID / BLOCK; ++i)
        e += partial[i * BLOCK + threadIdx.x];
    float bs = block_reduce(e, threadIdx.x);
    if (threadIdx.x == 0) out[0] = bs;   // overwrites poison
}

// Fallback (ws too small): single-kernel atomic path, same pipeline.
__global__ __launch_bounds__(BLOCK) void energy_atomic_kernel(
    const float* __restrict__ mean, const float* __restrict__ variance,
    const float* __restrict__ noise, const float* __restrict__ target,
    float* __restrict__ out) {
    const int wg  = (blockIdx.x & 7) * (GRID / 8) + (blockIdx.x >> 3);
    const int idx = wg * BLOCK + threadIdx.x;
    float e = energy_elem_mlp(mean, variance, noise, target, idx);
    float bs = block_reduce(e, threadIdx.x);
    if (threadIdx.x == 0) atomicAdd(out, bs);
}

extern "C" void kernel_launch(void* const* d_in, const int* in_sizes, int n_in,
                              void* d_out, int out_size, void* d_ws, size_t ws_size,
                              hipStream_t stream) {
    const float* mean     = (const float*)d_in[0];
    const float* variance = (const float*)d_in[1];
    const float* noise    = (const float*)d_in[2];
    const float* target   = (const float*)d_in[3];
    float* out = (float*)d_out;

    if (ws_size >= (size_t)GRID * sizeof(float)) {
        float* partial = (float*)d_ws;
        energy_partial_kernel<<<GRID, BLOCK, 0, stream>>>(mean, variance, noise,
                                                          target, partial);
        reduce_partial_kernel<<<1, BLOCK, 0, stream>>>(partial, out);
    } else {
        hipMemsetAsync(out, 0, sizeof(float), stream);
        energy_atomic_kernel<<<GRID, BLOCK, 0, stream>>>(mean, variance, noise,
                                                         target, out);
    }
}

// Round 10
// 33.231 us; speedup vs baseline: 1.1610x; 1.0171x over previous
//
#include <hip/hip_runtime.h>
#include <float.h>

#define NS 50
#define NP 64              // padded to power of two for bitonic network
#define B_DIM 8192
#define D_DIM 64
#define BD (B_DIM * D_DIM)
#define BLOCK 256
#define EPT 2
#define GRID2 (BD / (BLOCK * EPT))   // 1024 blocks

__device__ __forceinline__ float block_reduce(float e, int tid) {
    #pragma unroll
    for (int off = 32; off > 0; off >>= 1)
        e += __shfl_down(e, off, 64);
    __shared__ float wsum[BLOCK / 64];
    const int lane = tid & 63;
    const int wid  = tid >> 6;
    if (lane == 0) wsum[wid] = e;
    __syncthreads();
    float bs = 0.0f;
    if (tid == 0) {
        #pragma unroll
        for (int w = 0; w < BLOCK / 64; ++w) bs += wsum[w];
    }
    return bs;
}

// Verified bitonic pipeline (R2-R9): s[0..NS-1] raw noise, clobbered.
__device__ __forceinline__ float elem_energy(float* s, float m, float sd, float t) {
    float f0 = 0.0f, f1 = 0.0f;
    #pragma unroll
    for (int k = 0; k < NS; ++k) {
        s[k] = fmaf(s[k], sd, m);
        float d = fabsf(s[k] - t);
        if (k & 1) f1 += d;
        else       f0 += d;
    }
    #pragma unroll
    for (int k = NS; k < NP; ++k) s[k] = FLT_MAX;

    #pragma unroll
    for (int k = 2; k <= NP; k <<= 1) {
        #pragma unroll
        for (int j = k >> 1; j > 0; j >>= 1) {
            #pragma unroll
            for (int i = 0; i < NP; ++i) {
                const int l = i ^ j;
                if (l > i) {
                    const bool up = ((i & k) == 0);
                    float x = s[i], y = s[l];
                    float lo = fminf(x, y);
                    float hi = fmaxf(x, y);
                    s[i] = up ? lo : hi;
                    s[l] = up ? hi : lo;
                }
            }
        }
    }

    float p0 = 0.0f, p1 = 0.0f;
    #pragma unroll
    for (int k = 0; k < NS; ++k) {
        const float c = (float)(2 * k - (NS - 1));
        if (k & 1) p1 = fmaf(c, s[k], p1);
        else       p0 = fmaf(c, s[k], p0);
    }
    return (f0 + f1) * (1.0f / NS) - (p0 + p1) * (1.0f / 2450.0f);
}

// Two elements/thread via dwordx2 (512B per wave-request, half the request
// count per byte). Second halves parked in LDS (thread-private column, no
// barrier, bank-free layout) to dodge the R6 register-spill trap.
__device__ __forceinline__ float energy_pair(const float* __restrict__ mean,
                                             const float* __restrict__ variance,
                                             const float* __restrict__ noise,
                                             const float* __restrict__ target,
                                             float* park, int tid, int col0) {
    float2 f2[NS];
    const unsigned voff = (unsigned)col0 * 4u;
    #pragma unroll
    for (int k = 0; k < NS; ++k) {
        const unsigned off_k = voff + (unsigned)k * (unsigned)(BD * 4);
        asm volatile("global_load_dwordx2 %0, %1, %2"
                     : "=v"(f2[k])
                     : "v"(off_k), "s"(noise));
    }

    const float2 mv = *(const float2*)(mean + col0);
    const float2 vv = *(const float2*)(variance + col0);
    const float2 tv = *(const float2*)(target + col0);

    asm volatile("s_waitcnt vmcnt(0)" ::: "memory");
    __builtin_amdgcn_sched_barrier(0);

    // Park .y in LDS (layout [k][tid]: 2 lanes/bank = free), keep .x in regs.
    #pragma unroll
    for (int k = 0; k < NS; ++k) park[k * BLOCK + tid] = f2[k].y;

    float s[NP];
    #pragma unroll
    for (int k = 0; k < NS; ++k) s[k] = f2[k].x;
    float e = elem_energy(s, mv.x, sqrtf(vv.x + 1e-6f), tv.x);

    #pragma unroll
    for (int k = 0; k < NS; ++k) s[k] = park[k * BLOCK + tid];
    e += elem_energy(s, mv.y, sqrtf(vv.y + 1e-6f), tv.y);

    return e * (1.0f / (float)BD);
}

// Stage 1: XCD-swizzled (1024 % 8 == 0, bijective), plain partial store.
__global__ __launch_bounds__(BLOCK, 3) void energy_partial_kernel(
    const float* __restrict__ mean, const float* __restrict__ variance,
    const float* __restrict__ noise, const float* __restrict__ target,
    float* __restrict__ partial) {
    __shared__ float park[NS * BLOCK];   // 50 KB
    const int tid  = threadIdx.x;
    const int wg   = (blockIdx.x & 7) * (GRID2 / 8) + (blockIdx.x >> 3);
    const int col0 = wg * (BLOCK * EPT) + tid * EPT;
    float e = energy_pair(mean, variance, noise, target, park, tid, col0);
    float bs = block_reduce(e, tid);
    if (tid == 0) partial[blockIdx.x] = bs;
}

// Stage 2: one block sums the partials, writes the scalar output.
__global__ __launch_bounds__(BLOCK) void reduce_partial_kernel(
    const float* __restrict__ partial, float* __restrict__ out) {
    float e = 0.0f;
    #pragma unroll
    for (int i = 0; i < GRID2 / BLOCK; ++i)
        e += partial[i * BLOCK + threadIdx.x];
    float bs = block_reduce(e, threadIdx.x);
    if (threadIdx.x == 0) out[0] = bs;   // overwrites poison
}

// Fallback (ws too small): single-kernel atomic path, same pipeline.
__global__ __launch_bounds__(BLOCK, 3) void energy_atomic_kernel(
    const float* __restrict__ mean, const float* __restrict__ variance,
    const float* __restrict__ noise, const float* __restrict__ target,
    float* __restrict__ out) {
    __shared__ float park[NS * BLOCK];
    const int tid  = threadIdx.x;
    const int wg   = (blockIdx.x & 7) * (GRID2 / 8) + (blockIdx.x >> 3);
    const int col0 = wg * (BLOCK * EPT) + tid * EPT;
    float e = energy_pair(mean, variance, noise, target, park, tid, col0);
    float bs = block_reduce(e, tid);
    if (tid == 0) atomicAdd(out, bs);
}

extern "C" void kernel_launch(void* const* d_in, const int* in_sizes, int n_in,
                              void* d_out, int out_size, void* d_ws, size_t ws_size,
                              hipStream_t stream) {
    const float* mean     = (const float*)d_in[0];
    const float* variance = (const float*)d_in[1];
    const float* noise    = (const float*)d_in[2];
    const float* target   = (const float*)d_in[3];
    float* out = (float*)d_out;

    if (ws_size >= (size_t)GRID2 * sizeof(float)) {
        float* partial = (float*)d_ws;
        energy_partial_kernel<<<GRID2, BLOCK, 0, stream>>>(mean, variance, noise,
                                                           target, partial);
        reduce_partial_kernel<<<1, BLOCK, 0, stream>>>(partial, out);
    } else {
        hipMemsetAsync(out, 0, sizeof(float), stream);
        energy_atomic_kernel<<<GRID2, BLOCK, 0, stream>>>(mean, variance, noise,
                                                          target, out);
    }
}